// Round 11
// baseline (421.230 us; speedup 1.0000x reference)
//
#include <hip/hip_runtime.h>
#include <math.h>

#define N 6144
#define H 4
#define CAP 128
#define MINF 1e-15f
#define ONE_EPS  1.0000001192092896f   // fp32(1.0 + 1e-7)
#define ONE_MEPS 0.9999998807907104f   // fp32(1.0 - 1e-7)

__device__ __forceinline__ float wave_reduce_sum(float v) {
    v += __shfl_xor(v, 32, 64);
    v += __shfl_xor(v, 16, 64);
    v += __shfl_xor(v, 8, 64);
    v += __shfl_xor(v, 4, 64);
    v += __shfl_xor(v, 2, 64);
    v += __shfl_xor(v, 1, 64);
    return v;
}

__device__ __forceinline__ float arcosh_f(float z) {
    return logf(z + sqrtf(fmaxf(z * z - 1.0f, 0.0f)));
}

// ---------------- K1: prep = logmap0(x) + weight packs + cnt zero ----------------
// [0,1536): lmv; [1536,1728): pack Bp/Bo; [1728,1808): pack WlT; [1808,1832): cnt=0
__global__ void k_prep(const float* __restrict__ x, float* __restrict__ lmv,
                       const float* __restrict__ W_att, const float* __restrict__ W_data,
                       const float* __restrict__ W_out, const float* __restrict__ Wl,
                       float* __restrict__ Bp, float* __restrict__ Bo,
                       float* __restrict__ WlT, int* __restrict__ cnt) {
    int b = blockIdx.x;
    if (b < 1536) {
        int i = b * 4 + (threadIdx.x >> 6);
        int lane = threadIdx.x & 63;
        float y = x[i * 65 + 1 + lane];
        float ss = wave_reduce_sum(y * y);
        float n = fmaxf(sqrtf(ss), MINF);
        float t = fmaxf(x[i * 65], ONE_EPS);
        lmv[i * 64 + lane] = arcosh_f(t) * y / n;
    } else if (b < 1728) {
        int tid = (b - 1536) * 256 + threadIdx.x;
        int m = tid >> 12;
        int r = tid & 4095;
        int k = r >> 6, o = r & 63;
        const float* src;
        if (m < 4) src = W_att + m * 65 * 65;
        else if (m < 8) src = W_data + (m - 4) * 65 * 65;
        else src = W_out + (m - 8) * 65 * 65;
        float val = src[(1 + o) * 65 + (1 + k)];
        if (m < 8) Bp[m * 4096 + k * 64 + o] = val;
        else Bo[(m - 8) * 4096 + k * 64 + o] = val;
    } else if (b < 1808) {
        // WlT[k*320 + o] = Wl[(1+o)*257 + 1 + k] (o<259), else 0
        int L = ((b - 1728) * 256 + threadIdx.x) * 4;
        int k = L / 320, o0 = L % 320;
        float v[4];
        #pragma unroll
        for (int q = 0; q < 4; q++) {
            int o = o0 + q;
            v[q] = (o < 259) ? Wl[(size_t)(1 + o) * 257 + 1 + k] : 0.f;
        }
        *(float4*)(WlT + L) = make_float4(v[0], v[1], v[2], v[3]);
    } else {
        cnt[(b - 1808) * 256 + threadIdx.x] = 0;
    }
}

// ---------------- K2: heterogeneous: GEMM1+head-epilogue || CSR build ----------
__global__ void __launch_bounds__(256) k_csr_gemm(
        const float* __restrict__ adj, int* __restrict__ cnt, int* __restrict__ idx,
        const float* __restrict__ lmv, const float* __restrict__ Bp,
        float* __restrict__ attv, float2* __restrict__ a0l, float* __restrict__ pv) {
    __shared__ float smem[64 * 65];
    if (blockIdx.x < 768) {
        float (*As)[64] = (float(*)[64])smem;             // [16][64]
        float (*Bs)[64] = (float(*)[64])(smem + 1024);    // [16][64]
        float (*Cs)[65] = (float(*)[65])smem;             // [64][65], reuses As/Bs
        int my = blockIdx.x / 96;      // 0..3 W_att heads, 4..7 W_data heads
        int ix = blockIdx.x % 96;
        const float* Bb = Bp + (size_t)my * 4096;
        int i0 = ix * 64;
        int tid = threadIdx.x;
        int tx = tid & 15, ty = tid >> 4;
        float acc[4][4] = {};
        for (int k0 = 0; k0 < 64; k0 += 16) {
            {
                int mm = tid >> 2, kq = tid & 3;
                float4 v = *(const float4*)(lmv + (size_t)(i0 + mm) * 64 + k0 + kq * 4);
                As[kq * 4 + 0][mm] = v.x;
                As[kq * 4 + 1][mm] = v.y;
                As[kq * 4 + 2][mm] = v.z;
                As[kq * 4 + 3][mm] = v.w;
            }
            {
                int kk = tid >> 4, o4 = tid & 15;
                float4 bvv = *(const float4*)(Bb + (k0 + kk) * 64 + o4 * 4);
                *(float4*)&Bs[kk][o4 * 4] = bvv;
            }
            __syncthreads();
            #pragma unroll
            for (int kk = 0; kk < 16; kk++) {
                float4 av = *(const float4*)&As[kk][ty * 4];
                float4 bv = *(const float4*)&Bs[kk][tx * 4];
                float a[4] = {av.x, av.y, av.z, av.w};
                float b[4] = {bv.x, bv.y, bv.z, bv.w};
                #pragma unroll
                for (int r = 0; r < 4; r++)
                    #pragma unroll
                    for (int c = 0; c < 4; c++) acc[r][c] += a[r] * b[c];
            }
            __syncthreads();
        }
        #pragma unroll
        for (int r = 0; r < 4; r++)
            #pragma unroll
            for (int c = 0; c < 4; c++)
                Cs[ty * 4 + r][tx * 4 + c] = acc[r][c];
        __syncthreads();
        int w = tid >> 6, lane = tid & 63;
        bool isAtt = my < 4;
        int h = my & 3;
        #pragma unroll 1
        for (int r = 0; r < 16; r++) {
            int row = w * 16 + r;
            int i = i0 + row;
            float u = Cs[row][lane];
            float nn = fmaxf(sqrtf(wave_reduce_sum(u * u)), MINF);
            if (isAtt) {
                float sha = sinhf(nn);
                attv[((size_t)h * N + i) * 64 + lane] = sha * u / nn;
                if (lane == 0) a0l[h * N + i].x = coshf(nn);
            } else {
                float shd = sinhf(nn), chd = coshf(nn);
                float pvd = (shd * u / nn) / (chd + 1.0f);
                pv[((size_t)h * N + i) * 64 + lane] = pvd;
                float sp = wave_reduce_sum(pvd * pvd);
                if (lane == 0) a0l[h * N + i].y = 2.0f / fmaxf(1.0f - sp, MINF);
            }
        }
    } else {
        // 9 iterations/thread (9437184 = 9 * 1048576), 2 loads in flight
        const float4* a4 = (const float4*)adj;
        const unsigned STRIDE = 1048576u;
        unsigned e0 = (blockIdx.x - 768) * 256 + threadIdx.x;
        float4 v0 = a4[e0];
        float4 v1 = a4[e0 + STRIDE];
        #pragma unroll 1
        for (int it = 0; it < 9; it++) {
            float4 vn;
            if (it < 7) vn = a4[e0 + (unsigned)(it + 2) * STRIDE];
            unsigned base = (e0 + (unsigned)it * STRIDE) * 4u;
            float vals[4] = {v0.x, v0.y, v0.z, v0.w};
            #pragma unroll
            for (int q = 0; q < 4; q++) {
                if (vals[q] > 0.01f) {
                    unsigned t = base + q;
                    int j = t / N;
                    int i = t % N;
                    int pos = atomicAdd(&cnt[i], 1);
                    if (pos < CAP) idx[i * CAP + pos] = j;
                }
            }
            v0 = v1;
            v1 = vn;
        }
    }
}

// ---------------- K3: fused sparse attention ----------------
__global__ void __launch_bounds__(256) k_attn(
        const int* __restrict__ cnt, const int* __restrict__ idx,
        const float* __restrict__ attv, const float2* __restrict__ a0l,
        const float* __restrict__ pv, float* __restrict__ lm2) {
    __shared__ float wls[4][CAP];
    __shared__ int jls[4][CAP];
    int w = threadIdx.x >> 6, lane = threadIdx.x & 63;
    int i = blockIdx.x * 4 + w;
    int h = blockIdx.y;
    const float* attvh = attv + (size_t)h * N * 64;
    const float* pvh = pv + (size_t)h * N * 64;
    const float2* a0lh = a0l + (size_t)h * N;

    int c = lane & 3;
    float4 aireg[4];
    #pragma unroll
    for (int q = 0; q < 4; q++)
        aireg[q] = *(const float4*)(attvh + (size_t)i * 64 + q * 16 + c * 4);
    float ai0 = a0lh[i].x;
    int nn = min(cnt[i], CAP);

    float accd = 0.f, accss = 0.f;
    for (int base = 0; base < nn; base += 16) {
        int t = base + (lane >> 2);
        bool act = t < nn;
        int j = act ? idx[i * CAP + t] : i;
        float2 al = a0lh[j];
        float d = 0.f;
        #pragma unroll
        for (int q = 0; q < 4; q++) {
            float4 b = *(const float4*)(attvh + (size_t)j * 64 + q * 16 + c * 4);
            float4 a = aireg[q];
            d += a.x * b.x + a.y * b.y + a.z * b.z + a.w * b.w;
        }
        d += __shfl_xor(d, 1, 64);
        d += __shfl_xor(d, 2, 64);
        float theta = fmaxf(ai0 * al.x - d, ONE_EPS);
        float ar = arcosh_f(theta);
        float S = fminf(ar * ar, 50.0f);
        if (!act) S = 0.f;
        if (c == 0) {
            accd += S * (al.y - 1.0f);
            accss += S * S;
            wls[w][t] = S * al.y;
            jls[w][t] = j;
        }
    }
    accd = wave_reduce_sum(accd);
    accss = wave_reduce_sum(accss);
    float nrm = fmaxf(sqrtf(accss), 1e-12f);
    float den = fmaxf(accd / nrm, MINF);
    float scl = 1.0f / (nrm * den);

    float accn = 0.f;
    #pragma unroll 4
    for (int t = 0; t < nn; t++) {
        int j = jls[w][t];
        float wq = wls[w][t];
        accn = fmaf(wq, pvh[(size_t)j * 64 + lane], accn);
    }
    float v = -scl * accn;
    float nv = fmaxf(sqrtf(wave_reduce_sum(v * v)), MINF);
    float nc = fminf(nv, ONE_MEPS);
    float mh = tanhf(0.5f * atanhf(nc));
    float md = mh * v / nv;
    float s = wave_reduce_sum(md * md);
    float Dh = fmaxf(1.0f - s, MINF);
    float hb0 = (1.0f + s) / Dh;
    float hbv = 2.0f * md / Dh;
    float nh = fmaxf(2.0f * sqrtf(s) / Dh, MINF);
    float t2 = fmaxf(hb0, ONE_EPS);
    lm2[((size_t)h * N + i) * 64 + lane] = arcosh_f(t2) * hbv / nh;
}

// ---------------- K4: out-linear GEMM (4 heads) + 256-dim final logmap ----------
__global__ void __launch_bounds__(256) k_out_fused(
        const float* __restrict__ lm2, const float* __restrict__ Bo,
        float* __restrict__ lmF) {
    __shared__ float As[16][32];
    __shared__ float Bs[16][64];
    __shared__ float Ps[32][257];
    int i0 = blockIdx.x * 32;
    int tid = threadIdx.x;
    int tx = tid & 15, ty = tid >> 4;   // rows ty*2+{0,1}, cols tx*4..+3
    for (int h = 0; h < H; h++) {
        const float* Ab = lm2 + (size_t)h * N * 64;
        const float* Bb = Bo + (size_t)h * 4096;
        float acc[2][4] = {};
        for (int k0 = 0; k0 < 64; k0 += 16) {
            {
                int mm = tid & 31, kb = (tid >> 5) * 2;
                As[kb + 0][mm] = Ab[(size_t)(i0 + mm) * 64 + k0 + kb + 0];
                As[kb + 1][mm] = Ab[(size_t)(i0 + mm) * 64 + k0 + kb + 1];
            }
            {
                int o = tid & 63, kb = (tid >> 6) * 4;
                Bs[kb + 0][o] = Bb[(k0 + kb + 0) * 64 + o];
                Bs[kb + 1][o] = Bb[(k0 + kb + 1) * 64 + o];
                Bs[kb + 2][o] = Bb[(k0 + kb + 2) * 64 + o];
                Bs[kb + 3][o] = Bb[(k0 + kb + 3) * 64 + o];
            }
            __syncthreads();
            #pragma unroll
            for (int kk = 0; kk < 16; kk++) {
                float4 bv = *(const float4*)&Bs[kk][tx * 4];
                float a0 = As[kk][ty * 2 + 0];
                float a1 = As[kk][ty * 2 + 1];
                acc[0][0] += a0 * bv.x; acc[0][1] += a0 * bv.y;
                acc[0][2] += a0 * bv.z; acc[0][3] += a0 * bv.w;
                acc[1][0] += a1 * bv.x; acc[1][1] += a1 * bv.y;
                acc[1][2] += a1 * bv.z; acc[1][3] += a1 * bv.w;
            }
            __syncthreads();
        }
        #pragma unroll
        for (int r = 0; r < 2; r++)
            #pragma unroll
            for (int c2 = 0; c2 < 4; c2++)
                Ps[ty * 2 + r][h * 64 + tx * 4 + c2] = acc[r][c2];
        __syncthreads();
    }
    int w = tid >> 6, lane = tid & 63;
    #pragma unroll 1
    for (int r = 0; r < 8; r++) {
        int row = w * 8 + r;
        int i = i0 + row;
        float pr[4];
        float sp[4];
        #pragma unroll
        for (int h = 0; h < 4; h++) {
            float u = Ps[row][h * 64 + lane];
            float nv = fmaxf(sqrtf(wave_reduce_sum(u * u)), MINF);
            float sh = sinhf(nv), ch = coshf(nv);
            float pd = (sh * u / nv) / (ch + 1.0f);   // to_poincare(expmap0)
            pr[h] = pd;
            sp[h] = wave_reduce_sum(pd * pd);
        }
        float s = ((sp[0] + sp[1]) + sp[2]) + sp[3];
        float Dh = fmaxf(1.0f - s, MINF);
        float hb0 = (1.0f + s) / Dh;
        float nrm = fmaxf(2.0f * sqrtf(s) / Dh, MINF);
        float tt = fmaxf(hb0, ONE_EPS);
        float fac = arcosh_f(tt);
        #pragma unroll
        for (int h = 0; h < 4; h++) {
            float hbv = 2.0f * pr[h] / Dh;
            lmF[(size_t)i * 256 + h * 64 + lane] = fac * hbv / nrm;
        }
    }
}

// ---------------- K5: final GEMM (32-row tiles, 5 o-tiles from WlT) + epilogue ---
__global__ void __launch_bounds__(256) k_final_fused2(
        const float* __restrict__ A, const float* __restrict__ WlT,
        float* __restrict__ out) {
    __shared__ float As[16][32];
    __shared__ float Bs[16][64];
    __shared__ float Us[32][261];
    int i0 = blockIdx.x * 32;
    int tid = threadIdx.x;
    int tx = tid & 15, ty = tid >> 4;   // rows ty*2+{0,1}, cols tx*4..+3
    for (int co = 0; co < 5; co++) {
        int o0 = co * 64;
        float acc[2][4] = {};
        for (int k0 = 0; k0 < 256; k0 += 16) {
            {
                int mm = tid & 31, kb = (tid >> 5) * 2;
                As[kb + 0][mm] = A[(size_t)(i0 + mm) * 256 + k0 + kb + 0];
                As[kb + 1][mm] = A[(size_t)(i0 + mm) * 256 + k0 + kb + 1];
            }
            {
                int o = tid & 63, kb = (tid >> 6) * 4;
                Bs[kb + 0][o] = WlT[(size_t)(k0 + kb + 0) * 320 + o0 + o];
                Bs[kb + 1][o] = WlT[(size_t)(k0 + kb + 1) * 320 + o0 + o];
                Bs[kb + 2][o] = WlT[(size_t)(k0 + kb + 2) * 320 + o0 + o];
                Bs[kb + 3][o] = WlT[(size_t)(k0 + kb + 3) * 320 + o0 + o];
            }
            __syncthreads();
            #pragma unroll
            for (int kk = 0; kk < 16; kk++) {
                float4 bv = *(const float4*)&Bs[kk][tx * 4];
                float a0 = As[kk][ty * 2 + 0];
                float a1 = As[kk][ty * 2 + 1];
                acc[0][0] += a0 * bv.x; acc[0][1] += a0 * bv.y;
                acc[0][2] += a0 * bv.z; acc[0][3] += a0 * bv.w;
                acc[1][0] += a1 * bv.x; acc[1][1] += a1 * bv.y;
                acc[1][2] += a1 * bv.z; acc[1][3] += a1 * bv.w;
            }
            __syncthreads();
        }
        // GUARD (R5/R10 lesson): co=4 logical cols are 256..259 only; unguarded
        // stores would wrap into the next row of Us[32][261].
        #pragma unroll
        for (int r = 0; r < 2; r++)
            #pragma unroll
            for (int c2 = 0; c2 < 4; c2++) {
                int oc = o0 + tx * 4 + c2;
                if (oc < 260) Us[ty * 2 + r][oc] = acc[r][c2];
            }
        __syncthreads();
    }
    int w = tid >> 6, lane = tid & 63;
    #pragma unroll 1
    for (int r = 0; r < 8; r++) {
        int row = w * 8 + r;
        int i = i0 + row;
        float u0 = Us[row][lane];
        float u1 = Us[row][64 + lane];
        float u2 = Us[row][128 + lane];
        float u3 = Us[row][192 + lane];
        float u4 = (lane < 3) ? Us[row][256 + lane] : 0.f;
        float ss = wave_reduce_sum(u0 * u0 + u1 * u1 + u2 * u2 + u3 * u3 + u4 * u4);
        float nv = fmaxf(sqrtf(ss), MINF);
        float sh = sinhf(nv);
        float sc = sh / nv;
        out[(size_t)i * 260 + 1 + lane]   = sc * u0;
        out[(size_t)i * 260 + 65 + lane]  = sc * u1;
        out[(size_t)i * 260 + 129 + lane] = sc * u2;
        out[(size_t)i * 260 + 193 + lane] = sc * u3;
        if (lane < 3) out[(size_t)i * 260 + 257 + lane] = sc * u4;
        if (lane == 0) out[(size_t)i * 260] = sqrtf(1.0f + sh * sh);
    }
}

extern "C" void kernel_launch(void* const* d_in, const int* in_sizes, int n_in,
                              void* d_out, int out_size, void* d_ws, size_t ws_size,
                              hipStream_t stream) {
    const float* x = (const float*)d_in[0];
    const float* adj = (const float*)d_in[1];
    const float* W_att = (const float*)d_in[2];
    const float* W_data = (const float*)d_in[3];
    const float* W_out = (const float*)d_in[4];
    const float* W_lin = (const float*)d_in[5];
    float* out = (float*)d_out;

    char* ws = (char*)d_ws;
    size_t off = 0;
    auto alloc = [&](size_t bytes) {
        void* ptr = ws + off;
        off += (bytes + 255) & ~(size_t)255;
        return ptr;
    };
    int* cnt = (int*)alloc((size_t)N * 4);
    int* idx = (int*)alloc((size_t)N * CAP * 4);
    float* lmv = (float*)alloc((size_t)N * 64 * 4);
    float* attv = (float*)alloc((size_t)H * N * 64 * 4);  // reused as lmF later
    float2* a0l = (float2*)alloc((size_t)H * N * 8);
    float* pvb = (float*)alloc((size_t)H * N * 64 * 4);
    float* lm2 = (float*)alloc((size_t)H * N * 64 * 4);
    float* Bp = (float*)alloc((size_t)8 * 4096 * 4);
    float* Bo = (float*)alloc((size_t)4 * 4096 * 4);
    float* WlT = (float*)alloc((size_t)256 * 320 * 4);
    float* lmF = attv;   // alias: attv dead after k_attn

    k_prep<<<1832, 256, 0, stream>>>(x, lmv, W_att, W_data, W_out, W_lin,
                                     Bp, Bo, WlT, cnt);
    k_csr_gemm<<<4864, 256, 0, stream>>>(adj, cnt, idx, lmv, Bp, attv, a0l, pvb);
    k_attn<<<dim3(N / 4, H), 256, 0, stream>>>(cnt, idx, attv, a0l, pvb, lm2);
    k_out_fused<<<N / 32, 256, 0, stream>>>(lm2, Bo, lmF);
    k_final_fused2<<<N / 32, 256, 0, stream>>>(lmF, WlT, out);
}

// Round 12
// 335.885 us; speedup vs baseline: 1.2541x; 1.2541x over previous
//
#include <hip/hip_runtime.h>
#include <math.h>

#define N 6144
#define H 4
#define CAP 128
#define MINF 1e-15f
#define ONE_EPS  1.0000001192092896f   // fp32(1.0 + 1e-7)
#define ONE_MEPS 0.9999998807907104f   // fp32(1.0 - 1e-7)

__device__ __forceinline__ float wave_reduce_sum(float v) {
    v += __shfl_xor(v, 32, 64);
    v += __shfl_xor(v, 16, 64);
    v += __shfl_xor(v, 8, 64);
    v += __shfl_xor(v, 4, 64);
    v += __shfl_xor(v, 2, 64);
    v += __shfl_xor(v, 1, 64);
    return v;
}

__device__ __forceinline__ float arcosh_f(float z) {
    return logf(z + sqrtf(fmaxf(z * z - 1.0f, 0.0f)));
}

// ---------------- K1: prep = logmap0(x) + weight packs + cnt zero ----------------
// [0,1536): lmv; [1536,1728): pack Bp/Bo; [1728,1808): pack WlT; [1808,1832): cnt=0
__global__ void k_prep(const float* __restrict__ x, float* __restrict__ lmv,
                       const float* __restrict__ W_att, const float* __restrict__ W_data,
                       const float* __restrict__ W_out, const float* __restrict__ Wl,
                       float* __restrict__ Bp, float* __restrict__ Bo,
                       float* __restrict__ WlT, int* __restrict__ cnt) {
    int b = blockIdx.x;
    if (b < 1536) {
        int i = b * 4 + (threadIdx.x >> 6);
        int lane = threadIdx.x & 63;
        float y = x[i * 65 + 1 + lane];
        float ss = wave_reduce_sum(y * y);
        float n = fmaxf(sqrtf(ss), MINF);
        float t = fmaxf(x[i * 65], ONE_EPS);
        lmv[i * 64 + lane] = arcosh_f(t) * y / n;
    } else if (b < 1728) {
        int tid = (b - 1536) * 256 + threadIdx.x;
        int m = tid >> 12;
        int r = tid & 4095;
        int k = r >> 6, o = r & 63;
        const float* src;
        if (m < 4) src = W_att + m * 65 * 65;
        else if (m < 8) src = W_data + (m - 4) * 65 * 65;
        else src = W_out + (m - 8) * 65 * 65;
        float val = src[(1 + o) * 65 + (1 + k)];
        if (m < 8) Bp[m * 4096 + k * 64 + o] = val;
        else Bo[(m - 8) * 4096 + k * 64 + o] = val;
    } else if (b < 1808) {
        // WlT[k*320 + o] = Wl[(1+o)*257 + 1 + k] (o<259), else 0
        int L = ((b - 1728) * 256 + threadIdx.x) * 4;
        int k = L / 320, o0 = L % 320;
        float v[4];
        #pragma unroll
        for (int q = 0; q < 4; q++) {
            int o = o0 + q;
            v[q] = (o < 259) ? Wl[(size_t)(1 + o) * 257 + 1 + k] : 0.f;
        }
        *(float4*)(WlT + L) = make_float4(v[0], v[1], v[2], v[3]);
    } else {
        cnt[(b - 1808) * 256 + threadIdx.x] = 0;
    }
}

// ---------------- K2: heterogeneous: GEMM1+head-epilogue || CSR build ----------
// [0,768): 8 mats x 96 row-tiles (lmv @ Bp) + expmap/poincare epilogue
// [768,4864): depth-2-pipelined grid-stride scan of adj building CSR of adj^T
// LDS union: As/Bs (8 KB) overlap Cs (16.6 KB) -> 16.6 KB total, 8 blocks/CU.
__global__ void __launch_bounds__(256) k_csr_gemm(
        const float* __restrict__ adj, int* __restrict__ cnt, int* __restrict__ idx,
        const float* __restrict__ lmv, const float* __restrict__ Bp,
        float* __restrict__ attv, float2* __restrict__ a0l, float* __restrict__ pv) {
    __shared__ float smem[64 * 65];
    if (blockIdx.x < 768) {
        float (*As)[64] = (float(*)[64])smem;             // [16][64]
        float (*Bs)[64] = (float(*)[64])(smem + 1024);    // [16][64]
        float (*Cs)[65] = (float(*)[65])smem;             // [64][65], reuses As/Bs
        int my = blockIdx.x / 96;      // 0..3 W_att heads, 4..7 W_data heads
        int ix = blockIdx.x % 96;
        const float* Bb = Bp + (size_t)my * 4096;
        int i0 = ix * 64;
        int tid = threadIdx.x;
        int tx = tid & 15, ty = tid >> 4;
        float acc[4][4] = {};
        for (int k0 = 0; k0 < 64; k0 += 16) {
            {
                int mm = tid >> 2, kq = tid & 3;
                float4 v = *(const float4*)(lmv + (size_t)(i0 + mm) * 64 + k0 + kq * 4);
                As[kq * 4 + 0][mm] = v.x;
                As[kq * 4 + 1][mm] = v.y;
                As[kq * 4 + 2][mm] = v.z;
                As[kq * 4 + 3][mm] = v.w;
            }
            {
                int kk = tid >> 4, o4 = tid & 15;
                float4 bvv = *(const float4*)(Bb + (k0 + kk) * 64 + o4 * 4);
                *(float4*)&Bs[kk][o4 * 4] = bvv;
            }
            __syncthreads();
            #pragma unroll
            for (int kk = 0; kk < 16; kk++) {
                float4 av = *(const float4*)&As[kk][ty * 4];
                float4 bv = *(const float4*)&Bs[kk][tx * 4];
                float a[4] = {av.x, av.y, av.z, av.w};
                float b[4] = {bv.x, bv.y, bv.z, bv.w};
                #pragma unroll
                for (int r = 0; r < 4; r++)
                    #pragma unroll
                    for (int c = 0; c < 4; c++) acc[r][c] += a[r] * b[c];
            }
            __syncthreads();
        }
        #pragma unroll
        for (int r = 0; r < 4; r++)
            #pragma unroll
            for (int c = 0; c < 4; c++)
                Cs[ty * 4 + r][tx * 4 + c] = acc[r][c];
        __syncthreads();
        int w = tid >> 6, lane = tid & 63;
        bool isAtt = my < 4;
        int h = my & 3;
        #pragma unroll 1
        for (int r = 0; r < 16; r++) {
            int row = w * 16 + r;
            int i = i0 + row;
            float u = Cs[row][lane];
            float nn = fmaxf(sqrtf(wave_reduce_sum(u * u)), MINF);
            if (isAtt) {
                float sha = sinhf(nn);
                attv[((size_t)h * N + i) * 64 + lane] = sha * u / nn;
                if (lane == 0) a0l[h * N + i].x = coshf(nn);
            } else {
                float shd = sinhf(nn), chd = coshf(nn);
                float pvd = (shd * u / nn) / (chd + 1.0f);
                pv[((size_t)h * N + i) * 64 + lane] = pvd;
                float sp = wave_reduce_sum(pvd * pvd);
                if (lane == 0) a0l[h * N + i].y = 2.0f / fmaxf(1.0f - sp, MINF);
            }
        }
    } else {
        // 9 iterations/thread (9437184 = 9 * 1048576), 2 loads in flight
        const float4* a4 = (const float4*)adj;
        const unsigned STRIDE = 1048576u;
        unsigned e0 = (blockIdx.x - 768) * 256 + threadIdx.x;
        float4 v0 = a4[e0];
        float4 v1 = a4[e0 + STRIDE];
        #pragma unroll 1
        for (int it = 0; it < 9; it++) {
            float4 vn;
            if (it < 7) vn = a4[e0 + (unsigned)(it + 2) * STRIDE];
            unsigned base = (e0 + (unsigned)it * STRIDE) * 4u;
            float vals[4] = {v0.x, v0.y, v0.z, v0.w};
            #pragma unroll
            for (int q = 0; q < 4; q++) {
                if (vals[q] > 0.01f) {
                    unsigned t = base + q;
                    int j = t / N;
                    int i = t % N;
                    int pos = atomicAdd(&cnt[i], 1);
                    if (pos < CAP) idx[i * CAP + pos] = j;
                }
            }
            v0 = v1;
            v1 = vn;
        }
    }
}

// ---------------- K3: fused sparse attention ----------------
__global__ void __launch_bounds__(256) k_attn(
        const int* __restrict__ cnt, const int* __restrict__ idx,
        const float* __restrict__ attv, const float2* __restrict__ a0l,
        const float* __restrict__ pv, float* __restrict__ lm2) {
    __shared__ float wls[4][CAP];
    __shared__ int jls[4][CAP];
    int w = threadIdx.x >> 6, lane = threadIdx.x & 63;
    int i = blockIdx.x * 4 + w;
    int h = blockIdx.y;
    const float* attvh = attv + (size_t)h * N * 64;
    const float* pvh = pv + (size_t)h * N * 64;
    const float2* a0lh = a0l + (size_t)h * N;

    int c = lane & 3;
    float4 aireg[4];
    #pragma unroll
    for (int q = 0; q < 4; q++)
        aireg[q] = *(const float4*)(attvh + (size_t)i * 64 + q * 16 + c * 4);
    float ai0 = a0lh[i].x;
    int nn = min(cnt[i], CAP);

    float accd = 0.f, accss = 0.f;
    for (int base = 0; base < nn; base += 16) {
        int t = base + (lane >> 2);
        bool act = t < nn;
        int j = act ? idx[i * CAP + t] : i;
        float2 al = a0lh[j];
        float d = 0.f;
        #pragma unroll
        for (int q = 0; q < 4; q++) {
            float4 b = *(const float4*)(attvh + (size_t)j * 64 + q * 16 + c * 4);
            float4 a = aireg[q];
            d += a.x * b.x + a.y * b.y + a.z * b.z + a.w * b.w;
        }
        d += __shfl_xor(d, 1, 64);
        d += __shfl_xor(d, 2, 64);
        float theta = fmaxf(ai0 * al.x - d, ONE_EPS);
        float ar = arcosh_f(theta);
        float S = fminf(ar * ar, 50.0f);
        if (!act) S = 0.f;
        if (c == 0) {
            accd += S * (al.y - 1.0f);
            accss += S * S;
            wls[w][t] = S * al.y;
            jls[w][t] = j;
        }
    }
    accd = wave_reduce_sum(accd);
    accss = wave_reduce_sum(accss);
    float nrm = fmaxf(sqrtf(accss), 1e-12f);
    float den = fmaxf(accd / nrm, MINF);
    float scl = 1.0f / (nrm * den);

    float accn = 0.f;
    #pragma unroll 4
    for (int t = 0; t < nn; t++) {
        int j = jls[w][t];
        float wq = wls[w][t];
        accn = fmaf(wq, pvh[(size_t)j * 64 + lane], accn);
    }
    float v = -scl * accn;
    float nv = fmaxf(sqrtf(wave_reduce_sum(v * v)), MINF);
    float nc = fminf(nv, ONE_MEPS);
    float mh = tanhf(0.5f * atanhf(nc));
    float md = mh * v / nv;
    float s = wave_reduce_sum(md * md);
    float Dh = fmaxf(1.0f - s, MINF);
    float hb0 = (1.0f + s) / Dh;
    float hbv = 2.0f * md / Dh;
    float nh = fmaxf(2.0f * sqrtf(s) / Dh, MINF);
    float t2 = fmaxf(hb0, ONE_EPS);
    lm2[((size_t)h * N + i) * 64 + lane] = arcosh_f(t2) * hbv / nh;
}

// ---------------- K4: GEMM2 (per-head out linear) + expmap/to_poincare -> p -----
__global__ void __launch_bounds__(256) k_gemm_out(
        const float* __restrict__ lm2, const float* __restrict__ Bo,
        float* __restrict__ p) {
    __shared__ float As[16][64];
    __shared__ float Bs[16][64];
    __shared__ float Cs[64][65];
    int h = blockIdx.y;
    const float* Ab = lm2 + (size_t)h * N * 64;
    const float* Bb = Bo + (size_t)h * 4096;
    int i0 = blockIdx.x * 64;
    int tid = threadIdx.x;
    int tx = tid & 15, ty = tid >> 4;
    float acc[4][4] = {};
    for (int k0 = 0; k0 < 64; k0 += 16) {
        {
            int mm = tid >> 2, kq = tid & 3;
            float4 v = *(const float4*)(Ab + (size_t)(i0 + mm) * 64 + k0 + kq * 4);
            As[kq * 4 + 0][mm] = v.x;
            As[kq * 4 + 1][mm] = v.y;
            As[kq * 4 + 2][mm] = v.z;
            As[kq * 4 + 3][mm] = v.w;
        }
        {
            int kk = tid >> 4, o4 = tid & 15;
            float4 bvv = *(const float4*)(Bb + (k0 + kk) * 64 + o4 * 4);
            *(float4*)&Bs[kk][o4 * 4] = bvv;
        }
        __syncthreads();
        #pragma unroll
        for (int kk = 0; kk < 16; kk++) {
            float4 av = *(const float4*)&As[kk][ty * 4];
            float4 bv = *(const float4*)&Bs[kk][tx * 4];
            float a[4] = {av.x, av.y, av.z, av.w};
            float b[4] = {bv.x, bv.y, bv.z, bv.w};
            #pragma unroll
            for (int r = 0; r < 4; r++)
                #pragma unroll
                for (int c = 0; c < 4; c++) acc[r][c] += a[r] * b[c];
        }
        __syncthreads();
    }
    #pragma unroll
    for (int r = 0; r < 4; r++)
        #pragma unroll
        for (int c = 0; c < 4; c++)
            Cs[ty * 4 + r][tx * 4 + c] = acc[r][c];
    __syncthreads();
    int w = tid >> 6, lane = tid & 63;
    #pragma unroll 1
    for (int r16 = 0; r16 < 16; r16++) {
        int row = w * 16 + r16;
        int i = i0 + row;
        float u = Cs[row][lane];
        float nv = fmaxf(sqrtf(wave_reduce_sum(u * u)), MINF);
        float sh = sinhf(nv), ch = coshf(nv);
        p[(size_t)i * 256 + h * 64 + lane] = (sh * u / nv) / (ch + 1.0f);
    }
}

// ---------------- K5: final to_hyperboloid + logmap0 (256-dim) ----------------
__global__ void k_final_logmap(const float* __restrict__ p, float* __restrict__ lmF) {
    __shared__ float part[4];
    int i = blockIdx.x;
    int t = threadIdx.x;
    int w = t >> 6;
    float pd = p[(size_t)i * 256 + t];
    float ss = wave_reduce_sum(pd * pd);
    if ((t & 63) == 0) part[w] = ss;
    __syncthreads();
    float s = part[0] + part[1] + part[2] + part[3];
    float Dh = fmaxf(1.0f - s, MINF);
    float hb0 = (1.0f + s) / Dh;
    float hbv = 2.0f * pd / Dh;
    float n = fmaxf(2.0f * sqrtf(s) / Dh, MINF);
    float tt = fmaxf(hb0, ONE_EPS);
    lmF[(size_t)i * 256 + t] = arcosh_f(tt) * hbv / n;
}

// ---------------- K6: final GEMM (N,256)@(256,259->WlT) -> U (stride 260) -------
__global__ void __launch_bounds__(256) k_final_gemm(
        const float* __restrict__ A, const float* __restrict__ WlT,
        float* __restrict__ U) {
    __shared__ float As[16][64];
    __shared__ float Bs[16][64];
    int i0 = blockIdx.x * 64;
    int o0 = blockIdx.y * 64;
    int tid = threadIdx.x;
    int tx = tid & 15, ty = tid >> 4;
    float acc[4][4] = {};
    for (int k0 = 0; k0 < 256; k0 += 16) {
        {
            int mm = tid >> 2;
            int kq = tid & 3;
            const float4 v = *(const float4*)(A + (size_t)(i0 + mm) * 256 + k0 + kq * 4);
            As[kq * 4 + 0][mm] = v.x;
            As[kq * 4 + 1][mm] = v.y;
            As[kq * 4 + 2][mm] = v.z;
            As[kq * 4 + 3][mm] = v.w;
        }
        {
            int kk = tid >> 4, o4 = tid & 15;
            *(float4*)&Bs[kk][o4 * 4] =
                *(const float4*)(WlT + (size_t)(k0 + kk) * 320 + o0 + o4 * 4);
        }
        __syncthreads();
        #pragma unroll
        for (int kk = 0; kk < 16; kk++) {
            float4 av = *(const float4*)&As[kk][ty * 4];
            float4 bv = *(const float4*)&Bs[kk][tx * 4];
            float a[4] = {av.x, av.y, av.z, av.w};
            float b[4] = {bv.x, bv.y, bv.z, bv.w};
            #pragma unroll
            for (int r = 0; r < 4; r++)
                #pragma unroll
                for (int c = 0; c < 4; c++) acc[r][c] += a[r] * b[c];
        }
        __syncthreads();
    }
    #pragma unroll
    for (int r = 0; r < 4; r++) {
        int i = i0 + ty * 4 + r;
        #pragma unroll
        for (int c = 0; c < 4; c++) {
            int o = o0 + tx * 4 + c;
            if (o < 259) U[(size_t)i * 260 + o] = acc[r][c];
        }
    }
}

// ---------------- K7: final expmap0 + hyp_proj epilogue ----------------
__global__ void k_final_epilogue(const float* __restrict__ U, float* __restrict__ out) {
    __shared__ float part[4];
    int i = blockIdx.x;
    int t = threadIdx.x;
    float a = U[(size_t)i * 260 + t];
    float b = (t < 3) ? U[(size_t)i * 260 + 256 + t] : 0.f;
    float ss = wave_reduce_sum(a * a + b * b);
    if ((t & 63) == 0) part[t >> 6] = ss;
    __syncthreads();
    ss = part[0] + part[1] + part[2] + part[3];
    float nv = fmaxf(sqrtf(ss), MINF);
    float sh = sinhf(nv);
    float scale = sh / nv;
    out[(size_t)i * 260 + 1 + t] = scale * a;
    if (t < 3) out[(size_t)i * 260 + 257 + t] = scale * b;
    if (t == 0) out[(size_t)i * 260] = sqrtf(1.0f + sh * sh);
}

extern "C" void kernel_launch(void* const* d_in, const int* in_sizes, int n_in,
                              void* d_out, int out_size, void* d_ws, size_t ws_size,
                              hipStream_t stream) {
    const float* x = (const float*)d_in[0];
    const float* adj = (const float*)d_in[1];
    const float* W_att = (const float*)d_in[2];
    const float* W_data = (const float*)d_in[3];
    const float* W_out = (const float*)d_in[4];
    const float* W_lin = (const float*)d_in[5];
    float* out = (float*)d_out;

    char* ws = (char*)d_ws;
    size_t off = 0;
    auto alloc = [&](size_t bytes) {
        void* ptr = ws + off;
        off += (bytes + 255) & ~(size_t)255;
        return ptr;
    };
    int* cnt = (int*)alloc((size_t)N * 4);
    int* idx = (int*)alloc((size_t)N * CAP * 4);
    float* lmv = (float*)alloc((size_t)N * 64 * 4);
    float* attv = (float*)alloc((size_t)H * N * 64 * 4);  // reused as lmF later
    float2* a0l = (float2*)alloc((size_t)H * N * 8);
    float* pvb = (float*)alloc((size_t)H * N * 64 * 4);   // reused as p later
    float* lm2 = (float*)alloc((size_t)H * N * 64 * 4);
    float* Bp = (float*)alloc((size_t)8 * 4096 * 4);
    float* Bo = (float*)alloc((size_t)4 * 4096 * 4);
    float* WlT = (float*)alloc((size_t)256 * 320 * 4);
    float* U = (float*)alloc((size_t)N * 260 * 4);
    float* lmF = attv;   // alias: attv dead after k_attn
    float* p = pvb;      // alias: pv dead after k_attn

    k_prep<<<1832, 256, 0, stream>>>(x, lmv, W_att, W_data, W_out, W_lin,
                                     Bp, Bo, WlT, cnt);
    k_csr_gemm<<<4864, 256, 0, stream>>>(adj, cnt, idx, lmv, Bp, attv, a0l, pvb);
    k_attn<<<dim3(N / 4, H), 256, 0, stream>>>(cnt, idx, attv, a0l, pvb, lm2);
    k_gemm_out<<<dim3(N / 64, H), 256, 0, stream>>>(lm2, Bo, p);
    k_final_logmap<<<N, 256, 0, stream>>>(p, lmF);
    k_final_gemm<<<dim3(N / 64, 5), 256, 0, stream>>>(lmF, WlT, U);
    k_final_epilogue<<<N, 256, 0, stream>>>(U, out);
}